// Round 5
// baseline (324.750 us; speedup 1.0000x reference)
//
#include <hip/hip_runtime.h>
#include <hip/hip_bf16.h>
#include <math.h>

#define B_ 16
#define S_ 256
#define D_ 1024
#define HP_ 16
#define DK_ 64
#define HC_ 8
#define SK_ 32
#define EPS_ 1e-6f

// alpha = sqrt(log2(e)/sqrt(dk)): applied to BOTH q and k at projection time so
// that QK^T already carries log2e/sqrt(dk) and softmax is a bare exp2.
#define ALPHA_P 0.42466089973135876f   // dk=64 (positional attention)
#define ALPHA_C 0.50500991942f         // dk=32 (channel attention)

typedef __attribute__((ext_vector_type(8))) short short8v;
typedef __attribute__((ext_vector_type(4))) float f32x4;

__device__ __forceinline__ float bf2f(unsigned short h) {
    return __uint_as_float((unsigned)h << 16);
}
// packed f32x2 -> bf16x2 RNE (v_cvt_pk_bf16_f32 on gfx950)
__device__ __forceinline__ ushort2 f2bf2(float a, float b) {
    __hip_bfloat162 h = __float22bfloat162_rn(make_float2(a, b));
    union { __hip_bfloat162 h2; ushort2 u2; } cv;
    cv.h2 = h;
    return cv.u2;
}
// 2^x via v_exp_f32; s_nop 0 satisfies the 1-cycle TRANS->consumer wait state.
__device__ __forceinline__ float exp2_fast(float x) {
    float r;
    asm("v_exp_f32 %0, %1\n\ts_nop 0" : "=v"(r) : "v"(x));
    return r;
}
// async global->LDS, 16B per lane; LDS dest = wave-uniform base + lane*16
__device__ __forceinline__ void ldlds16(const unsigned short* g, unsigned short* l) {
    const unsigned int* gp = reinterpret_cast<const unsigned int*>(g);
    auto* lp = reinterpret_cast<__attribute__((address_space(3))) unsigned int*>(
        reinterpret_cast<uintptr_t>(l));
    __builtin_amdgcn_global_load_lds(gp, lp, 16, 0, 0);
}

// ---------------- K1: LayerNorm over channels -> bf16 hi/lo split ---------------
__global__ __launch_bounds__(256) void k1_ln_p(
    const float* __restrict__ x, const float* __restrict__ a_p,
    const float* __restrict__ b_p, unsigned short* __restrict__ xh,
    unsigned short* __restrict__ xl)
{
    const int row = blockIdx.x;                  // b*S + s
    const float4* xr = (const float4*)(x + (size_t)row * D_);
    const int tid = threadIdx.x;
    float4 v = xr[tid];
    float s  = v.x + v.y + v.z + v.w;
    float sq = v.x*v.x + v.y*v.y + v.z*v.z + v.w*v.w;
    #pragma unroll
    for (int off = 32; off > 0; off >>= 1) {
        s  += __shfl_down(s, off);
        sq += __shfl_down(sq, off);
    }
    __shared__ float red[8];
    const int wid = tid >> 6, lane = tid & 63;
    if (lane == 0) { red[wid] = s; red[4 + wid] = sq; }
    __syncthreads();
    if (tid == 0) {
        float S0 = red[0] + red[1] + red[2] + red[3];
        float Q0 = red[4] + red[5] + red[6] + red[7];
        float mean = S0 / (float)D_;
        float var  = fmaxf((Q0 - (float)D_ * mean * mean) / (float)(D_ - 1), 0.0f);
        red[0] = mean;
        red[1] = 1.0f / (sqrtf(var) + EPS_);     // torch std(): unbiased; eps on std
    }
    __syncthreads();
    const float mean = red[0], inv = red[1];
    float4 a = ((const float4*)a_p)[tid];
    float4 b = ((const float4*)b_p)[tid];
    float o0 = a.x * (v.x - mean) * inv + b.x;
    float o1 = a.y * (v.y - mean) * inv + b.y;
    float o2 = a.z * (v.z - mean) * inv + b.z;
    float o3 = a.w * (v.w - mean) * inv + b.w;
    ushort2 h01 = f2bf2(o0, o1), h23 = f2bf2(o2, o3);
    ushort2 l01 = f2bf2(o0 - bf2f(h01.x), o1 - bf2f(h01.y));
    ushort2 l23 = f2bf2(o2 - bf2f(h23.x), o3 - bf2f(h23.y));
    ushort4 hv, lv;
    hv.x = h01.x; hv.y = h01.y; hv.z = h23.x; hv.w = h23.y;
    lv.x = l01.x; lv.y = l01.y; lv.z = l23.x; lv.w = l23.y;
    *(ushort4*)&xh[(size_t)row * D_ + tid*4] = hv;
    *(ushort4*)&xl[(size_t)row * D_ + tid*4] = lv;
}

// ------------- Transpose + bf16-split weights: W[k][n] -> T[n][k] hi/lo ---------
__global__ __launch_bounds__(256) void tsplit(
    const float* __restrict__ W, unsigned short* __restrict__ Th,
    unsigned short* __restrict__ Tl, int K, int N)
{
    const int z = blockIdx.z;
    W  += (size_t)z * K * N;
    Th += (size_t)z * K * N;
    Tl += (size_t)z * K * N;
    const int k0 = blockIdx.x * 64, n0 = blockIdx.y * 64;
    __shared__ float tile[64][65];
    const int ix = threadIdx.x & 63, iy = threadIdx.x >> 6;
    #pragma unroll
    for (int u = 0; u < 16; u++) {
        const int kk = iy*16 + u;
        tile[kk][ix] = W[(size_t)(k0+kk)*N + n0 + ix];
    }
    __syncthreads();
    #pragma unroll
    for (int u = 0; u < 16; u += 2) {
        const int nn0 = iy*16 + u, nn1 = nn0 + 1;
        const float v0 = tile[ix][nn0], v1 = tile[ix][nn1];
        ushort2 h2 = f2bf2(v0, v1);
        ushort2 l2 = f2bf2(v0 - bf2f(h2.x), v1 - bf2f(h2.y));
        Th[(size_t)(n0+nn0)*K + k0 + ix] = h2.x;
        Th[(size_t)(n0+nn1)*K + k0 + ix] = h2.y;
        Tl[(size_t)(n0+nn0)*K + k0 + ix] = l2.x;
        Tl[(size_t)(n0+nn1)*K + k0 + ix] = l2.y;
    }
}

// ------------- Split-bf16 MFMA GEMM, 256x128 tile, 3-deep ring, counted vmcnt ---
// T3+T4 (learn_hip m218/m201): LDS ring of 3 k-tile buffers (48 KB each, 144 KB);
// during tile t issue tile t+2's 6 DMA ops -> at tile entry outstanding =
// [t's 6, t+1's 6] and s_waitcnt vmcnt(6) waits ONLY tile t -> 6 loads stay in
// flight across every barrier (vmcnt(0) only on the last tile). 4 phases per
// tile: {ds_read A-frag pair || issue 2 DMA -> s_barrier -> lgkmcnt(0) +
// sched_barrier(0) -> setprio(1) -> 12 MFMA -> setprio(0)} (T5 pays on
// phase-split schedules). 8 waves (4M x 2N), wave tile 64x64.
// LDS XOR-swizzle (pitch 32 shorts): chunk(row,cc) at p = row*4+(cc^((row>>1)&3)).
// XCD-chunked bijective remap; 128 blocks per z (logical>>7 = z index).
// OUTMODE 1: zeff<zsplit -> bf16 hi/lo row-major (alpha) to Cout1+zeff*sC;
//            else -> bf16 hi/lo transposed per TB rows to Cout2.
// OUTMODE 3: f32 transposed per TB rows to Cout2.
#define MF3(i, j, ah, al)                                                          \
    acc[i][j] = __builtin_amdgcn_mfma_f32_16x16x32_bf16(ah, bhf[j], acc[i][j], 0, 0, 0); \
    acc[i][j] = __builtin_amdgcn_mfma_f32_16x16x32_bf16(ah, blf[j], acc[i][j], 0, 0, 0); \
    acc[i][j] = __builtin_amdgcn_mfma_f32_16x16x32_bf16(al, bhf[j], acc[i][j], 0, 0, 0);

#define PHASE(p, ISSUE)                                                            \
    {                                                                              \
        short8v ah_ = *(const short8v*)&Ash[cur][0][aFr[p]];                       \
        short8v al_ = *(const short8v*)&Ash[cur][1][aFr[p]];                       \
        ISSUE                                                                      \
        __builtin_amdgcn_s_barrier();                                              \
        asm volatile("s_waitcnt lgkmcnt(0)" ::: "memory");                         \
        __builtin_amdgcn_sched_barrier(0);                                         \
        __builtin_amdgcn_s_setprio(1);                                             \
        MF3(p, 0, ah_, al_) MF3(p, 1, ah_, al_)                                    \
        MF3(p, 2, ah_, al_) MF3(p, 3, ah_, al_)                                    \
        __builtin_amdgcn_s_setprio(0);                                             \
    }

template<int OUTMODE>
__global__ __launch_bounds__(512, 2) void mm_ring(
    const unsigned short* __restrict__ Ah, const unsigned short* __restrict__ Al,
    const unsigned short* __restrict__ Bh, const unsigned short* __restrict__ Bl,
    const float* __restrict__ bias, void* __restrict__ Cout1,
    void* __restrict__ Cout2,
    int M, int N, int K, long sB, long sBias, long sC, long loff, int TB,
    float alpha, int zsplit, int zobase, int lognx)
{
    const int nwg = gridDim.x * gridDim.y;
    const int chunk = nwg >> 3;
    const int flat = blockIdx.x + gridDim.x * blockIdx.y;
    const int logical = (flat & 7) * chunk + (flat >> 3);
    const int bz  = logical >> 7;          // 128 blocks per z
    const int rem = logical & 127;
    const int bx  = rem & ((1 << lognx) - 1);
    const int by  = rem >> lognx;
    const int zeff = bz + zobase;
    Bh   += (size_t)bz * sB;
    Bl   += (size_t)bz * sB;
    bias += (size_t)zeff * sBias;
    const int n0 = bx * 128, m0 = by * 256;
    __shared__ __align__(16) unsigned short Ash[3][2][256*32];   // 96 KB ring
    __shared__ __align__(16) unsigned short Bsh[3][2][128*32];   // 48 KB ring
    const int tid = threadIdx.x;
    const int wave = tid >> 6, lane = tid & 63;
    const int wm = wave & 3, wn = wave >> 2;      // wave tile 64(m) x 64(n)
    const int lrow = lane & 15, quad = lane >> 4;
    // DMA source offsets. A: chunks p = j*512+tid (j=0,1); B: p = tid.
    size_t gaOff[2];
    int cbA[2];
    #pragma unroll
    for (int j = 0; j < 2; j++) {
        const int p = j*512 + tid;
        const int row = p >> 2;
        const int cc = (p & 3) ^ ((row >> 1) & 3);
        gaOff[j] = (size_t)(m0 + row) * K + cc*8;
        cbA[j] = (j*512 + wave*64) * 8;
    }
    size_t gbOff;
    int cbB;
    {
        const int row = tid >> 2;
        const int cc = (tid & 3) ^ ((row >> 1) & 3);
        gbOff = (size_t)(n0 + row) * K + cc*8;
        cbB = (wave*64) * 8;
    }
    // fragment read offsets (swizzled)
    int aFr[4], bFr[4];
    #pragma unroll
    for (int i = 0; i < 4; i++) {
        const int ra = wm*64 + i*16 + lrow;
        aFr[i] = ((ra << 2) | (quad ^ ((ra >> 1) & 3))) * 8;
        const int rb = wn*64 + i*16 + lrow;
        bFr[i] = ((rb << 2) | (quad ^ ((rb >> 1) & 3))) * 8;
    }
    f32x4 acc[4][4];
    #pragma unroll
    for (int j = 0; j < 4; j++) {
        const float bv = bias[n0 + wn*64 + j*16 + lrow];
        #pragma unroll
        for (int i = 0; i < 4; i++) {
            acc[i][j][0] = bv; acc[i][j][1] = bv; acc[i][j][2] = bv; acc[i][j][3] = bv;
        }
    }
    // stage: 6 DMA ops per thread per k-tile (B h/l, A j=0 h/l, A j=1 h/l)
    #define STAGE6(t, buf)                                           \
        {                                                            \
            const int kk_ = (t) * 32;                                \
            ldlds16(Bh + gbOff     + kk_, &Bsh[buf][0][cbB]);        \
            ldlds16(Bl + gbOff     + kk_, &Bsh[buf][1][cbB]);        \
            ldlds16(Ah + gaOff[0]  + kk_, &Ash[buf][0][cbA[0]]);     \
            ldlds16(Al + gaOff[0]  + kk_, &Ash[buf][1][cbA[0]]);     \
            ldlds16(Ah + gaOff[1]  + kk_, &Ash[buf][0][cbA[1]]);     \
            ldlds16(Al + gaOff[1]  + kk_, &Ash[buf][1][cbA[1]]);     \
        }
    const int NT = K >> 5;
    // prologue: tiles 0 and 1 into ring slots 0,1 (12 ops outstanding)
    STAGE6(0, 0)
    STAGE6(1, 1)
    int cur = 0;
    for (int kt = 0; kt < NT; kt++) {
        // counted wait: outstanding = [tile kt: 6][tile kt+1: 6] -> vmcnt(6)
        // waits only tile kt; tile kt+1's loads stay in flight across barrier.
        if (kt == NT - 1) {
            asm volatile("s_waitcnt vmcnt(0)" ::: "memory");
        } else {
            asm volatile("s_waitcnt vmcnt(6)" ::: "memory");
        }
        __builtin_amdgcn_s_barrier();           // tile kt visible to all waves;
                                                // all kt-1 fragment reads retired
        const int nx2 = (cur >= 1) ? cur - 1 : 2;   // (cur+2)%3: slot for kt+2
        short8v bhf[4], blf[4];
        #pragma unroll
        for (int j = 0; j < 4; j++) {
            bhf[j] = *(const short8v*)&Bsh[cur][0][bFr[j]];
            blf[j] = *(const short8v*)&Bsh[cur][1][bFr[j]];
        }
        PHASE(0,
            if (kt + 2 < NT) {
                const int kk2 = (kt + 2) * 32;
                ldlds16(Bh + gbOff + kk2, &Bsh[nx2][0][cbB]);
                ldlds16(Bl + gbOff + kk2, &Bsh[nx2][1][cbB]);
            })
        PHASE(1,
            if (kt + 2 < NT) {
                const int kk2 = (kt + 2) * 32;
                ldlds16(Ah + gaOff[0] + kk2, &Ash[nx2][0][cbA[0]]);
                ldlds16(Al + gaOff[0] + kk2, &Ash[nx2][1][cbA[0]]);
            })
        PHASE(2,
            if (kt + 2 < NT) {
                const int kk2 = (kt + 2) * 32;
                ldlds16(Ah + gaOff[1] + kk2, &Ash[nx2][0][cbA[1]]);
                ldlds16(Al + gaOff[1] + kk2, &Ash[nx2][1][cbA[1]]);
            })
        PHASE(3, )
        cur = (cur + 1 == 3) ? 0 : cur + 1;
    }
    #undef STAGE6
    // C/D layout: col = lane&15, row = quad*4 + reg  [m89/m91-verified]
    #pragma unroll
    for (int i = 0; i < 4; i++) {
        const int mrow = m0 + wm*64 + i*16 + quad*4;
        #pragma unroll
        for (int j = 0; j < 4; j++) {
            const int ncol = n0 + wn*64 + j*16 + lrow;
            if (OUTMODE == 1) {
                if (zeff < zsplit) {
                    unsigned short* Ch = (unsigned short*)Cout1 + (size_t)zeff * sC;
                    unsigned short* Cl = Ch + loff;
                    #pragma unroll
                    for (int r = 0; r < 4; r += 2) {
                        const float v0 = acc[i][j][r] * alpha;
                        const float v1 = acc[i][j][r+1] * alpha;
                        ushort2 h2 = f2bf2(v0, v1);
                        ushort2 l2 = f2bf2(v0 - bf2f(h2.x), v1 - bf2f(h2.y));
                        Ch[(size_t)(mrow + r    ) * N + ncol] = h2.x;
                        Ch[(size_t)(mrow + r + 1) * N + ncol] = h2.y;
                        Cl[(size_t)(mrow + r    ) * N + ncol] = l2.x;
                        Cl[(size_t)(mrow + r + 1) * N + ncol] = l2.y;
                    }
                } else {
                    unsigned short* Ch = (unsigned short*)Cout2;
                    unsigned short* Cl = Ch + loff;
                    const int bidx = mrow / TB, t0 = mrow % TB;
                    const size_t ad = (size_t)bidx * N * TB + (size_t)ncol * TB + t0;
                    const float v0 = acc[i][j][0], v1 = acc[i][j][1];
                    const float v2 = acc[i][j][2], v3 = acc[i][j][3];
                    ushort2 h01 = f2bf2(v0, v1), h23 = f2bf2(v2, v3);
                    ushort2 l01 = f2bf2(v0 - bf2f(h01.x), v1 - bf2f(h01.y));
                    ushort2 l23 = f2bf2(v2 - bf2f(h23.x), v3 - bf2f(h23.y));
                    ushort4 hv, lv;
                    hv.x = h01.x; hv.y = h01.y; hv.z = h23.x; hv.w = h23.y;
                    lv.x = l01.x; lv.y = l01.y; lv.z = l23.x; lv.w = l23.y;
                    *(ushort4*)&Ch[ad] = hv;
                    *(ushort4*)&Cl[ad] = lv;
                }
            } else {
                // f32 transposed: out[bidx][ncol][t0..t0+3], one b128 store
                float* C = (float*)Cout2;
                const int bidx = mrow / TB, t0 = mrow % TB;
                f32x4 a4 = acc[i][j];
                *(float4*)&C[((size_t)bidx * N + ncol) * TB + t0] = *(float4*)&a4;
            }
        }
    }
}

// ------- K3: positional attention, MFMA flash, S^T=K*Q^T trick ------------------
// 2-phase double-buffered DMA staging: one raw s_barrier + vmcnt(0) per K-tile;
// tile kt+1 issued right after the barrier so HBM/L2 latency hides under compute.
// q,k pre-scaled by ALPHA_P at projection -> scores carry log2e/sqrt(dk); p=2^s.
// K/V LDS: pitch 64 shorts, swizzle p = row*8 + (cc ^ (row&7)). XCD-chunked grid.
__global__ __launch_bounds__(256) void k3_mfma(
    const unsigned short* __restrict__ qh, const unsigned short* __restrict__ ql,
    const unsigned short* __restrict__ kh, const unsigned short* __restrict__ kl,
    const unsigned short* __restrict__ vth, const unsigned short* __restrict__ vtl,
    float* __restrict__ out)
{
    // grid (4,16,16); HW round-robins flat id over 8 XCDs -> give each XCD a
    // contiguous chunk of 128 logical blocks = 32 complete (h,b) K/V sets.
    const int flat = blockIdx.x + (blockIdx.y << 2) + (blockIdx.z << 6);
    const int logical = ((flat & 7) << 7) | (flat >> 3);
    const int m0 = (logical & 3) * 64;
    const int h  = (logical >> 2) & 15;
    const int b  = logical >> 6;
    const int hoff = h * DK_;
    const size_t rowb = (size_t)b * S_;
    __shared__ __align__(16) unsigned short Ksh[2][64*64], Ksl[2][64*64];
    __shared__ __align__(16) unsigned short VTh[2][64*64], VTl[2][64*64];
    __shared__ __align__(16) unsigned short Ps[64][72];
    const int tid = threadIdx.x;
    const int w = tid >> 6, lane = tid & 63;
    const int lrow = lane & 15, quad = lane >> 4;
    // Q as B-operand (cols of S^T): hi/lo, 2 k-steps
    short8v bqh[2], bql[2];
    #pragma unroll
    for (int ks = 0; ks < 2; ks++) {
        const size_t qb = (rowb + m0 + w*16 + lrow) * D_ + hoff + ks*32 + quad*8;
        bqh[ks] = *(const short8v*)&qh[qb];
        bql[ks] = *(const short8v*)&ql[qb];
    }
    size_t kOff[2], vOff[2];
    int cb[2];
    #pragma unroll
    for (int j = 0; j < 2; j++) {
        const int p = w*128 + j*64 + lane;
        const int row = p >> 3;
        const int cc = (p & 7) ^ (row & 7);
        kOff[j] = (rowb + row) * D_ + hoff + cc*8;
        vOff[j] = ((size_t)b * D_ + hoff + row) * S_ + cc*8;
        cb[j] = (w*128 + j*64) * 8;
    }
    f32x4 o[4] = {};
    float lacc = 0.f;
    // prologue: stage tile 0 into buf 0
    #pragma unroll
    for (int j = 0; j < 2; j++) {
        ldlds16(kh  + kOff[j], &Ksh[0][cb[j]]);
        ldlds16(kl  + kOff[j], &Ksl[0][cb[j]]);
        ldlds16(vth + vOff[j], &VTh[0][cb[j]]);
        ldlds16(vtl + vOff[j], &VTl[0][cb[j]]);
    }
    for (int kt = 0; kt < 4; kt++) {
        const int cur = kt & 1;
        asm volatile("s_waitcnt vmcnt(0)" ::: "memory"); // own tile-kt DMA done
        asm volatile("s_barrier" ::: "memory");          // all waves: tile visible;
                                                         // all done reading buf[cur^1]
        if (kt < 3) {                                    // prefetch tile kt+1
            const int n01 = (kt + 1) * 64;
            #pragma unroll
            for (int j = 0; j < 2; j++) {
                ldlds16(kh  + kOff[j] + (size_t)n01 * D_, &Ksh[cur^1][cb[j]]);
                ldlds16(kl  + kOff[j] + (size_t)n01 * D_, &Ksl[cur^1][cb[j]]);
                ldlds16(vth + vOff[j] + n01,              &VTh[cur^1][cb[j]]);
                ldlds16(vtl + vOff[j] + n01,              &VTl[cur^1][cb[j]]);
            }
        }
        // S^T = K·Q^T: rows=keys (A=K), cols=queries (B=Q regs)
        f32x4 sa[4] = {};
        #pragma unroll
        for (int ks = 0; ks < 2; ks++) {
            #pragma unroll
            for (int jk = 0; jk < 4; jk++) {
                const int r = jk*16 + lrow, c = ks*4 + quad;
                const int off = ((r << 3) | (c ^ (r & 7))) * 8;
                short8v akh = *(const short8v*)&Ksh[cur][off];
                short8v akl = *(const short8v*)&Ksl[cur][off];
                sa[jk] = __builtin_amdgcn_mfma_f32_16x16x32_bf16(akh, bqh[ks], sa[jk], 0, 0, 0);
                sa[jk] = __builtin_amdgcn_mfma_f32_16x16x32_bf16(akl, bqh[ks], sa[jk], 0, 0, 0);
                sa[jk] = __builtin_amdgcn_mfma_f32_16x16x32_bf16(akh, bql[ks], sa[jk], 0, 0, 0);
            }
        }
        // p = 2^s (scale folded upstream); P[m][key] row-major, b64 per frag
        #pragma unroll
        for (int jk = 0; jk < 4; jk++) {
            float p0 = exp2_fast(sa[jk][0]);
            float p1 = exp2_fast(sa[jk][1]);
            float p2 = exp2_fast(sa[jk][2]);
            float p3 = exp2_fast(sa[jk][3]);
            lacc += (p0 + p1) + (p2 + p3);
            ushort2 p01 = f2bf2(p0, p1), p23 = f2bf2(p2, p3);
            ushort4 ph;
            ph.x = p01.x; ph.y = p01.y; ph.z = p23.x; ph.w = p23.y;
            *(ushort4*)&Ps[w*16 + lrow][jk*16 + quad*4] = ph;   // wave-private rows
        }
        // PV: O = P·V^T' — no barrier (wave-private P)
        #pragma unroll
        for (int ks = 0; ks < 2; ks++) {
            short8v ap = *(const short8v*)&Ps[w*16 + lrow][ks*32 + quad*8];
            #pragma unroll
            for (int nf = 0; nf < 4; nf++) {
                const int r = nf*16 + lrow, c = ks*4 + quad;
                const int off = ((r << 3) | (c ^ (r & 7))) * 8;
                short8v vH = *(const short8v*)&VTh[cur][off];
                short8v vL = *(const short8v*)&VTl[cur][off];
                o[nf] = __builtin_amdgcn_mfma_f32_16x16x32_bf16(ap, vH, o[nf], 0, 0, 0);
                o[nf] = __builtin_amdgcn_mfma_f32_16x16x32_bf16(ap, vL, o[nf], 0, 0, 0);
            }
        }
    }
    // l: lane holds partials for col m=lrow (its quad's keys) -> sum over quads
    lacc += __shfl_xor(lacc, 16);
    lacc += __shfl_xor(lacc, 32);
    #pragma unroll
    for (int r = 0; r < 4; r++) {
        const float linv = 1.0f / __shfl(lacc, quad*4 + r);
        #pragma unroll
        for (int nf = 0; nf < 4; nf++)
            out[(rowb + m0 + w*16 + quad*4 + r) * D_ + hoff + nf*16 + lrow] =
                o[nf][r] * linv;
    }
}

// ------- K6: channel attention, MFMA flash, S^T trick ---------------------------
// Same 2-phase double-buffered single-barrier structure as k3. dk=32.
// Wave owns 32 q-rows (2 m-frags). P hi-only b64. Out bf16 h/l.
// K LDS: pitch 32 (swz (row>>1)&3); V LDS: pitch 64 (swz row&7). XCD-chunked grid.
__global__ __launch_bounds__(256) void k6_mfma(
    const unsigned short* __restrict__ qch, const unsigned short* __restrict__ qcl,
    const unsigned short* __restrict__ kch, const unsigned short* __restrict__ kcl,
    const unsigned short* __restrict__ vth, const unsigned short* __restrict__ vtl,
    unsigned short* __restrict__ oh, unsigned short* __restrict__ ol)
{
    // grid (8,8,16): each XCD gets 128 contiguous logicals = 16 complete (h,b)
    // K/V working sets -> K/V fetched once per XCD instead of 8x.
    const int flat = blockIdx.x + (blockIdx.y << 3) + (blockIdx.z << 6);
    const int logical = ((flat & 7) << 7) | (flat >> 3);
    const int m0 = (logical & 7) << 7;
    const int h  = (logical >> 3) & 7;
    const int b  = logical >> 6;
    const int hoff = h * SK_;
    const size_t rowb = (size_t)b * D_;
    __shared__ __align__(16) unsigned short Ksh[2][64*32], Ksl[2][64*32];
    __shared__ __align__(16) unsigned short VTh[2][32*64], VTl[2][32*64];
    __shared__ __align__(16) unsigned short Ps[128][72];
    const int tid = threadIdx.x;
    const int w = tid >> 6, lane = tid & 63;
    const int lrow = lane & 15, quad = lane >> 4;
    short8v bqh[2], bql[2];
    #pragma unroll
    for (int i = 0; i < 2; i++) {
        const size_t qb = (rowb + m0 + w*32 + i*16 + lrow) * S_ + hoff + quad*8;
        bqh[i] = *(const short8v*)&qch[qb];
        bql[i] = *(const short8v*)&qcl[qb];
    }
    size_t kOff, vOff;
    {
        const int pK = w*64 + lane;
        const int rowK = pK >> 2;
        const int ccK = (pK & 3) ^ ((rowK >> 1) & 3);
        kOff = (rowb + rowK) * S_ + hoff + ccK*8;
        const int pV = w*64 + lane;
        const int rowV = pV >> 3;
        const int ccV = (pV & 7) ^ (rowV & 7);
        vOff = ((size_t)b * S_ + hoff + rowV) * D_ + ccV*8;
    }
    const int cb = w*64*8;
    f32x4 o[2][2] = {};
    float lacc[2] = {0.f, 0.f};
    // prologue: stage tile 0 into buf 0
    ldlds16(kch + kOff, &Ksh[0][cb]);
    ldlds16(kcl + kOff, &Ksl[0][cb]);
    ldlds16(vth + vOff, &VTh[0][cb]);
    ldlds16(vtl + vOff, &VTl[0][cb]);
    for (int kt = 0; kt < 16; kt++) {
        const int cur = kt & 1;
        asm volatile("s_waitcnt vmcnt(0)" ::: "memory"); // own tile-kt DMA done
        asm volatile("s_barrier" ::: "memory");          // all waves: tile visible;
                                                         // all done reading buf[cur^1]
        if (kt < 15) {                                   // prefetch tile kt+1
            const int n01 = (kt + 1) * 64;
            ldlds16(kch + kOff + (size_t)n01 * S_, &Ksh[cur^1][cb]);
            ldlds16(kcl + kOff + (size_t)n01 * S_, &Ksl[cur^1][cb]);
            ldlds16(vth + vOff + n01,              &VTh[cur^1][cb]);
            ldlds16(vtl + vOff + n01,              &VTl[cur^1][cb]);
        }
        // S^T = K·Q^T  (q,k pre-scaled by ALPHA_C)
        f32x4 sa[2][4] = {};
        #pragma unroll
        for (int jk = 0; jk < 4; jk++) {
            const int r = jk*16 + lrow;
            const int off = ((r << 2) | (quad ^ ((r >> 1) & 3))) * 8;
            short8v akh = *(const short8v*)&Ksh[cur][off];
            short8v akl = *(const short8v*)&Ksl[cur][off];
            #pragma unroll
            for (int i = 0; i < 2; i++) {
                sa[i][jk] = __builtin_amdgcn_mfma_f32_16x16x32_bf16(akh, bqh[i], sa[i][jk], 0, 0, 0);
                sa[i][jk] = __builtin_amdgcn_mfma_f32_16x16x32_bf16(akl, bqh[i], sa[i][jk], 0, 0, 0);
                sa[i][jk] = __builtin_amdgcn_mfma_f32_16x16x32_bf16(akh, bql[i], sa[i][jk], 0, 0, 0);
            }
        }
        // p = 2^s; P row-major [m][key], b64 writes, wave-private rows
        #pragma unroll
        for (int i = 0; i < 2; i++)
            #pragma unroll
            for (int jk = 0; jk < 4; jk++) {
                float p0 = exp2_fast(sa[i][jk][0]);
                float p1 = exp2_fast(sa[i][jk][1]);
                float p2 = exp2_fast(sa[i][jk][2]);
                float p3 = exp2_fast(sa[i][jk][3]);
                lacc[i] += (p0 + p1) + (p2 + p3);
                ushort2 p01 = f2bf2(p0, p1), p23 = f2bf2(p2, p3);
                ushort4 ph;
                ph.x = p01.x; ph.y = p01.y; ph.z = p23.x; ph.w = p23.y;
                *(ushort4*)&Ps[w*32 + i*16 + lrow][jk*16 + quad*4] = ph;
            }
        // PV (no barrier: P rows wave-private)
        #pragma unroll
        for (int ks = 0; ks < 2; ks++) {
            short8v ap[2];
            #pragma unroll
            for (int i = 0; i < 2; i++)
                ap[i] = *(const short8v*)&Ps[w*32 + i*16 + lrow][ks*32 + quad*8];
            #pragma unroll
            for (int nf = 0; nf < 2; nf++) {
                const int r = nf*16 + lrow, c = ks*4 + quad;
                const int off = ((r << 3) | (c ^ (r & 7))) * 8;
                short8v vHf = *(const short8v*)&VTh[cur][off];
                short8v vLf = *(const short8v*)&VTl[cur][off];
                #pragma unroll
                for (int i = 0; i < 2; i++) {
                    o[i][nf] = __builtin_amdgcn_mfma_f32_16x16x32_bf16(ap[i], vHf, o[i][nf], 0, 0, 0);
                    o[i][nf] = __builtin_amdgcn_mfma_f32_16x16x32_bf16(ap[i], vLf, o[i][nf], 0, 0, 0);
                }
            }
        }
    }
    #pragma unroll
    for (int i = 0; i < 2; i++) {
        lacc[i] += __shfl_xor(lacc[i], 16);
        lacc[i] += __shfl_xor(lacc[i], 32);
    }
    #pragma unroll
    for (int i = 0; i < 2; i++)
        #pragma unroll
        for (int r = 0; r < 4; r++) {
            const float linv = 1.0f / __shfl(lacc[i], quad*4 + r);
            const float v0 = o[i][0][r] * linv;
            const float v1 = o[i][1][r] * linv;
            ushort2 h2 = f2bf2(v0, v1);
            ushort2 l2 = f2bf2(v0 - bf2f(h2.x), v1 - bf2f(h2.y));
            const size_t idx =
                (rowb + m0 + w*32 + i*16 + quad*4 + r) * S_ + hoff + lrow;
            oh[idx]      = h2.x;
            oh[idx + 16] = h2.y;
            ol[idx]      = l2.x;
            ol[idx + 16] = l2.y;
        }
}

// ------- K4 fused: LN over seq (stats+normalize) + transpose, bf16 h/l out ------
// Block = (64 d-cols, one b). tile[256][65] f32 + partials. One pass over x.
__global__ __launch_bounds__(256) void k4_fused(
    const float* __restrict__ x, const float* __restrict__ a_c,
    const float* __restrict__ b_c, unsigned short* __restrict__ xth,
    unsigned short* __restrict__ xtl)
{
    const int d0 = blockIdx.x * 64, b = blockIdx.y;
    __shared__ float tile[256][65];
    __shared__ float part[8][64];
    __shared__ float stats[2][64];
    __shared__ float acs[256], bcs[256];
    const int tid = threadIdx.x;
    acs[tid] = a_c[tid];
    bcs[tid] = b_c[tid];
    const int dl = tid & 63, sq = tid >> 6;
    float s1 = 0.f, s2 = 0.f;
    #pragma unroll 8
    for (int u = 0; u < 64; u++) {
        const int srow = sq*64 + u;
        const float v = x[((size_t)(b*S_ + srow))*D_ + d0 + dl];
        tile[srow][dl] = v;
        s1 += v; s2 += v*v;
    }
    part[sq][dl] = s1; part[4+sq][dl] = s2;
    __syncthreads();
    if (tid < 64) {
        const float S = part[0][tid]+part[1][tid]+part[2][tid]+part[3][tid];
        const float Q = part[4][tid]+part[5][tid]+part[6][tid]+part[7][tid];
        const float mean = S / (float)S_;
        const float var  = fmaxf((Q - (float)S_*mean*mean)/(float)(S_-1), 0.f);
        stats[0][tid] = mean;
        stats[1][tid] = 1.f/(sqrtf(var)+EPS_);
    }
    __syncthreads();
    const int dd = tid >> 2, s00 = (tid & 3) * 64;
    const float mean = stats[0][dd], inv = stats[1][dd];
    const size_t obase = ((size_t)(b*D_ + d0 + dd))*S_ + s00;
    #pragma unroll
    for (int c = 0; c < 8; c++) {
        union { ushort u[8]; uint4 v4; } hb, lb;
        #pragma unroll
        for (int t = 0; t < 8; t += 2) {
            const int s = s00 + c*8 + t;
            const float v0 = acs[s]  *(tile[s][dd]  -mean)*inv + bcs[s];
            const float v1 = acs[s+1]*(tile[s+1][dd]-mean)*inv + bcs[s+1];
            ushort2 h2 = f2bf2(v0, v1);
            ushort2 l2 = f2bf2(v0 - bf2f(h2.x), v1 - bf2f(h2.y));
            hb.u[t] = h2.x; hb.u[t+1] = h2.y;
            lb.u[t] = l2.x; lb.u[t+1] = l2.y;
        }
        *(uint4*)&xth[obase + c*8] = hb.v4;
        *(uint4*)&xtl[obase + c*8] = lb.v4;
    }
}

extern "C" void kernel_launch(void* const* d_in, const int* in_sizes, int n_in,
                              void* d_out, int out_size, void* d_ws, size_t ws_size,
                              hipStream_t stream)
{
    const float* x   = (const float*)d_in[0];
    const float* Wp  = (const float*)d_in[1];
    const float* bp  = (const float*)d_in[2];
    const float* Wc  = (const float*)d_in[3];
    const float* bc  = (const float*)d_in[4];
    const float* a_p = (const float*)d_in[5];
    const float* b_p = (const float*)d_in[6];
    const float* a_c = (const float*)d_in[7];
    const float* b_c = (const float*)d_in[8];
    float* out = (float*)d_out;
    float* ws  = (float*)d_ws;
    const size_t NE = (size_t)B_ * S_ * D_;     // 4,194,304

    float* S0 = ws;             // xp h/l -> attn f32 -> vcT h/l
    float* S1 = ws + NE;        // q h/l -> xt h/l -> xcatt h/l
    float* S2 = ws + 2*NE;      // k h/l -> qc h/l
    float* S3 = ws + 3*NE;      // vT h/l -> kc h/l
    unsigned short* SW = (unsigned short*)(ws + 4*NE);

    const size_t baseBytes = 4*NE*sizeof(float);
    const bool big = ws_size >= baseBytes + (size_t)2 * 3 * D_ * D_ * sizeof(unsigned short) * 2;

    unsigned short* xh = (unsigned short*)S0;
    unsigned short* xl = xh + NE;
    unsigned short* q_h  = (unsigned short*)S1;
    unsigned short* k_h  = (unsigned short*)S2;
    unsigned short* vt_h = (unsigned short*)S3;

    // 1) LayerNorm over channels -> bf16 hi/lo
    k1_ln_p<<<dim3(B_*S_), 256, 0, stream>>>(x, a_p, b_p, xh, xl);

    // 2) QKV projection (256x128 ring-3 GEMM, z in grid): q,k row-major bf16 h/l
    //    (pre-scaled by ALPHA_P); v transposed bf16 h/l.
    if (big) {
        unsigned short* WTh = SW;
        unsigned short* WTl = WTh + (size_t)3 * D_ * D_;
        tsplit<<<dim3(D_/64, D_/64, 3), 256, 0, stream>>>(Wp, WTh, WTl, D_, D_);
        mm_ring<1><<<dim3(128, 3), 512, 0, stream>>>(
            xh, xl, WTh, WTl, bp, (void*)q_h, (void*)vt_h,
            B_*S_, D_, D_, (long)D_*D_, (long)D_, (long)(2*NE), (long)NE, S_,
            ALPHA_P, 2, 0, 3);
    } else {
        unsigned short* WTh = SW;
        unsigned short* WTl = WTh + (size_t)D_ * D_;
        for (int z = 0; z < 3; z++) {
            tsplit<<<dim3(D_/64, D_/64, 1), 256, 0, stream>>>(
                Wp + (size_t)z*D_*D_, WTh, WTl, D_, D_);
            mm_ring<1><<<dim3(128, 1), 512, 0, stream>>>(
                xh, xl, WTh, WTl, bp, (void*)q_h, (void*)vt_h,
                B_*S_, D_, D_, 0, (long)D_, (long)(2*NE), (long)NE, S_,
                ALPHA_P, 2, z, 3);
        }
    }

    // 3) positional attention (MFMA flash, S^T trick) -> attn f32 in S0 (xp dead)
    k3_mfma<<<dim3(S_/64, HP_, B_), 256, 0, stream>>>(
        q_h, q_h + NE, k_h, k_h + NE, vt_h, vt_h + NE, S0);

    // 4) fused LN over sequence + transpose -> xt bf16 h/l in S1 (q dead)
    unsigned short* xth = (unsigned short*)S1;
    k4_fused<<<dim3(D_/64, B_), 256, 0, stream>>>(S0, a_c, b_c, xth, xth + NE);

    // 5) channel weights + channel QKV (256x128 ring-3 GEMM, z in grid): qc,kc
    //    row-major (pre-scaled by ALPHA_C); vc transposed
    unsigned short* WcTh = SW;
    unsigned short* WcTl = WcTh + (size_t)4 * S_ * S_;
    tsplit<<<dim3(S_/64, S_/64, 4), 256, 0, stream>>>(Wc, WcTh, WcTl, S_, S_);
    unsigned short* qc_h  = (unsigned short*)S2;   // k dead
    unsigned short* vct_h = (unsigned short*)S0;   // attn f32 dead after k4
    mm_ring<1><<<dim3(128, 3), 512, 0, stream>>>(
        xth, xth + NE, WcTh, WcTl, bc, (void*)qc_h, (void*)vct_h,
        B_*D_, S_, S_, (long)S_*S_, (long)S_, (long)(2*NE), (long)NE, D_,
        ALPHA_C, 2, 0, 1);

    // 6) channel attention (MFMA flash, S^T trick) -> xcatt bf16 h/l in S1 (xt dead)
    unsigned short* kc_h = (unsigned short*)S3;
    unsigned short* xch  = (unsigned short*)S1;
    k6_mfma<<<dim3(D_/128, HC_, B_), 256, 0, stream>>>(
        qc_h, qc_h + NE, kc_h, kc_h + NE, vct_h, vct_h + NE, xch, xch + NE);

    // 7) final projection -> out directly (f32 transposed epilogue)
    mm_ring<3><<<dim3(128, 1), 512, 0, stream>>>(
        xch, xch + NE, WcTh + (size_t)3*S_*S_, WcTl + (size_t)3*S_*S_, bc + 3*S_,
        nullptr, (void*)out, B_*D_, S_, S_, 0, 0, 0, 0, D_, 1.0f, 0, 0, 1);
}

// Round 6
// 284.919 us; speedup vs baseline: 1.1398x; 1.1398x over previous
//
#include <hip/hip_runtime.h>
#include <hip/hip_bf16.h>
#include <math.h>

#define B_ 16
#define S_ 256
#define D_ 1024
#define HP_ 16
#define DK_ 64
#define HC_ 8
#define SK_ 32
#define EPS_ 1e-6f

// alpha = sqrt(log2(e)/sqrt(dk)): applied to BOTH q and k at projection time so
// that QK^T already carries log2e/sqrt(dk) and softmax is a bare exp2.
#define ALPHA_P 0.42466089973135876f   // dk=64 (positional attention)
#define ALPHA_C 0.50500991942f         // dk=32 (channel attention)

typedef __attribute__((ext_vector_type(8))) short short8v;
typedef __attribute__((ext_vector_type(4))) float f32x4;

__device__ __forceinline__ float bf2f(unsigned short h) {
    return __uint_as_float((unsigned)h << 16);
}
// packed f32x2 -> bf16x2 RNE (v_cvt_pk_bf16_f32 on gfx950)
__device__ __forceinline__ ushort2 f2bf2(float a, float b) {
    __hip_bfloat162 h = __float22bfloat162_rn(make_float2(a, b));
    union { __hip_bfloat162 h2; ushort2 u2; } cv;
    cv.h2 = h;
    return cv.u2;
}
// 2^x via v_exp_f32; s_nop 0 satisfies the 1-cycle TRANS->consumer wait state.
__device__ __forceinline__ float exp2_fast(float x) {
    float r;
    asm("v_exp_f32 %0, %1\n\ts_nop 0" : "=v"(r) : "v"(x));
    return r;
}
// async global->LDS, 16B per lane; LDS dest = wave-uniform base + lane*16
__device__ __forceinline__ void ldlds16(const unsigned short* g, unsigned short* l) {
    const unsigned int* gp = reinterpret_cast<const unsigned int*>(g);
    auto* lp = reinterpret_cast<__attribute__((address_space(3))) unsigned int*>(
        reinterpret_cast<uintptr_t>(l));
    __builtin_amdgcn_global_load_lds(gp, lp, 16, 0, 0);
}

// ---------------- K1: LayerNorm over channels -> bf16 hi/lo split ---------------
__global__ __launch_bounds__(256) void k1_ln_p(
    const float* __restrict__ x, const float* __restrict__ a_p,
    const float* __restrict__ b_p, unsigned short* __restrict__ xh,
    unsigned short* __restrict__ xl)
{
    const int row = blockIdx.x;                  // b*S + s
    const float4* xr = (const float4*)(x + (size_t)row * D_);
    const int tid = threadIdx.x;
    float4 v = xr[tid];
    float s  = v.x + v.y + v.z + v.w;
    float sq = v.x*v.x + v.y*v.y + v.z*v.z + v.w*v.w;
    #pragma unroll
    for (int off = 32; off > 0; off >>= 1) {
        s  += __shfl_down(s, off);
        sq += __shfl_down(sq, off);
    }
    __shared__ float red[8];
    const int wid = tid >> 6, lane = tid & 63;
    if (lane == 0) { red[wid] = s; red[4 + wid] = sq; }
    __syncthreads();
    if (tid == 0) {
        float S0 = red[0] + red[1] + red[2] + red[3];
        float Q0 = red[4] + red[5] + red[6] + red[7];
        float mean = S0 / (float)D_;
        float var  = fmaxf((Q0 - (float)D_ * mean * mean) / (float)(D_ - 1), 0.0f);
        red[0] = mean;
        red[1] = 1.0f / (sqrtf(var) + EPS_);     // torch std(): unbiased; eps on std
    }
    __syncthreads();
    const float mean = red[0], inv = red[1];
    float4 a = ((const float4*)a_p)[tid];
    float4 b = ((const float4*)b_p)[tid];
    float o0 = a.x * (v.x - mean) * inv + b.x;
    float o1 = a.y * (v.y - mean) * inv + b.y;
    float o2 = a.z * (v.z - mean) * inv + b.z;
    float o3 = a.w * (v.w - mean) * inv + b.w;
    ushort2 h01 = f2bf2(o0, o1), h23 = f2bf2(o2, o3);
    ushort2 l01 = f2bf2(o0 - bf2f(h01.x), o1 - bf2f(h01.y));
    ushort2 l23 = f2bf2(o2 - bf2f(h23.x), o3 - bf2f(h23.y));
    ushort4 hv, lv;
    hv.x = h01.x; hv.y = h01.y; hv.z = h23.x; hv.w = h23.y;
    lv.x = l01.x; lv.y = l01.y; lv.z = l23.x; lv.w = l23.y;
    *(ushort4*)&xh[(size_t)row * D_ + tid*4] = hv;
    *(ushort4*)&xl[(size_t)row * D_ + tid*4] = lv;
}

// ------------- Transpose + bf16-split weights: W[k][n] -> T[n][k] hi/lo ---------
__global__ __launch_bounds__(256) void tsplit(
    const float* __restrict__ W, unsigned short* __restrict__ Th,
    unsigned short* __restrict__ Tl, int K, int N)
{
    const int z = blockIdx.z;
    W  += (size_t)z * K * N;
    Th += (size_t)z * K * N;
    Tl += (size_t)z * K * N;
    const int k0 = blockIdx.x * 64, n0 = blockIdx.y * 64;
    __shared__ float tile[64][65];
    const int ix = threadIdx.x & 63, iy = threadIdx.x >> 6;
    #pragma unroll
    for (int u = 0; u < 16; u++) {
        const int kk = iy*16 + u;
        tile[kk][ix] = W[(size_t)(k0+kk)*N + n0 + ix];
    }
    __syncthreads();
    #pragma unroll
    for (int u = 0; u < 16; u += 2) {
        const int nn0 = iy*16 + u, nn1 = nn0 + 1;
        const float v0 = tile[ix][nn0], v1 = tile[ix][nn1];
        ushort2 h2 = f2bf2(v0, v1);
        ushort2 l2 = f2bf2(v0 - bf2f(h2.x), v1 - bf2f(h2.y));
        Th[(size_t)(n0+nn0)*K + k0 + ix] = h2.x;
        Th[(size_t)(n0+nn1)*K + k0 + ix] = h2.y;
        Tl[(size_t)(n0+nn0)*K + k0 + ix] = l2.x;
        Tl[(size_t)(n0+nn1)*K + k0 + ix] = l2.y;
    }
}

// ------------- Split-bf16 MFMA GEMM, z-fused 128x64 tile, 2 blocks/CU -----------
// Geometry chosen for TLP (the round-1..4 invariant was 1 block/CU starvation):
// tile 128(M)x64(N) per z, Z weight matrices fused (A staged once), 4 waves
// (2m x 2n, wave tile 64x32), BK=32, double-buffered LDS = 80 KB (Z=3) ->
// EXACTLY 2 blocks/CU, grid 512 = 2/CU with zero tail. One block's vmcnt drain
// overlaps the other block's MFMA phase (m114 implicit wave-level overlap).
// Schedule per k-step (round-1-verified): vmcnt(0); s_barrier; issue kt+1 DMA
// into buf^1; ds_read + 72*Z/3 MFMA from buf[cur].
// LDS XOR-swizzle (pitch 32 shorts): chunk(row,cc) at p = row*4+(cc^((row>>1)&3)).
// XCD-chunked bijective remap on a 1D grid (nwg % 8 == 0).
// OUTMODE 1: zeff<zsplit -> bf16 hi/lo row-major (alpha) to Cout1+zeff*sC;
//            else -> bf16 hi/lo transposed per TB rows to Cout2.
// OUTMODE 3: f32 transposed per TB rows to Cout2.
template<int OUTMODE, int Z>
__global__ __launch_bounds__(256, 2) void mm_z(
    const unsigned short* __restrict__ Ah, const unsigned short* __restrict__ Al,
    const unsigned short* __restrict__ Bh, const unsigned short* __restrict__ Bl,
    const float* __restrict__ bias, void* __restrict__ Cout1,
    void* __restrict__ Cout2,
    int M, int N, int K, long sB, long sBias, long sC, long loff, int TB,
    float alpha, int zsplit, int zobase, int lognx)
{
    const int nwg = gridDim.x;
    const int chunk = nwg >> 3;
    const int flat = blockIdx.x;
    const int logical = (flat & 7) * chunk + (flat >> 3);
    const int bx = logical & ((1 << lognx) - 1);
    const int by = logical >> lognx;
    const int n0 = bx * 64, m0 = by * 128;
    __shared__ __align__(16) unsigned short Ash[2][2][128*32];     // 32 KB
    __shared__ __align__(16) unsigned short Bsh[2][Z][2][64*32];   // Z=3: 48 KB
    const int tid = threadIdx.x;
    const int wave = tid >> 6, lane = tid & 63;
    const int wm = wave & 1, wn = wave >> 1;      // wave tile 64(m) x 32(n)
    const int lrow = lane & 15, quad = lane >> 4;
    // DMA source offsets. A: 512 chunks, p = j*256+tid (j=0,1); B: 256, p = tid.
    size_t gaOff[2];
    int cbA[2];
    #pragma unroll
    for (int j = 0; j < 2; j++) {
        const int p = j*256 + tid;
        const int row = p >> 2;
        const int cc = (p & 3) ^ ((row >> 1) & 3);
        gaOff[j] = (size_t)(m0 + row) * K + cc*8;
        cbA[j] = (j*256 + wave*64) * 8;
    }
    size_t gbOff;
    int cbB;
    {
        const int row = tid >> 2;
        const int cc = (tid & 3) ^ ((row >> 1) & 3);
        gbOff = (size_t)(n0 + row) * K + cc*8;
        cbB = (wave*64) * 8;
    }
    // fragment read offsets (swizzled)
    int aFr[4], bFr[2];
    #pragma unroll
    for (int i = 0; i < 4; i++) {
        const int ra = wm*64 + i*16 + lrow;
        aFr[i] = ((ra << 2) | (quad ^ ((ra >> 1) & 3))) * 8;
    }
    #pragma unroll
    for (int j = 0; j < 2; j++) {
        const int rb = wn*32 + j*16 + lrow;
        bFr[j] = ((rb << 2) | (quad ^ ((rb >> 1) & 3))) * 8;
    }
    f32x4 acc[Z][4][2];
    #pragma unroll
    for (int z = 0; z < Z; z++)
        #pragma unroll
        for (int j = 0; j < 2; j++) {
            const float bv = bias[(size_t)(z + zobase) * sBias + n0 + wn*32 + j*16 + lrow];
            #pragma unroll
            for (int i = 0; i < 4; i++) {
                acc[z][i][j][0] = bv; acc[z][i][j][1] = bv;
                acc[z][i][j][2] = bv; acc[z][i][j][3] = bv;
            }
        }
    // stage one k-tile (10 DMA ops/thread at Z=3): A h/l x2 chunks + Z x B h/l
    #define STAGEZ(t, buf)                                                     \
        {                                                                      \
            const int kk_ = (t) * 32;                                          \
            _Pragma("unroll")                                                  \
            for (int j = 0; j < 2; j++) {                                      \
                ldlds16(Ah + gaOff[j] + kk_, &Ash[buf][0][cbA[j]]);            \
                ldlds16(Al + gaOff[j] + kk_, &Ash[buf][1][cbA[j]]);            \
            }                                                                  \
            _Pragma("unroll")                                                  \
            for (int z = 0; z < Z; z++) {                                      \
                ldlds16(Bh + (size_t)z * sB + gbOff + kk_, &Bsh[buf][z][0][cbB]); \
                ldlds16(Bl + (size_t)z * sB + gbOff + kk_, &Bsh[buf][z][1][cbB]); \
            }                                                                  \
        }
    const int NT = K >> 5;
    STAGEZ(0, 0)
    for (int kt = 0; kt < NT; kt++) {
        const int cur = kt & 1;
        asm volatile("s_waitcnt vmcnt(0)" ::: "memory"); // own tile-kt DMA done
        asm volatile("s_barrier" ::: "memory");          // tile visible to all;
                                                         // all done reading buf^1
        if (kt + 1 < NT)                                 // prefetch tile kt+1;
            STAGEZ(kt + 1, cur ^ 1)                      // lands during compute
        short8v bhf[Z][2], blf[Z][2];
        #pragma unroll
        for (int z = 0; z < Z; z++)
            #pragma unroll
            for (int j = 0; j < 2; j++) {
                bhf[z][j] = *(const short8v*)&Bsh[cur][z][0][bFr[j]];
                blf[z][j] = *(const short8v*)&Bsh[cur][z][1][bFr[j]];
            }
        #pragma unroll
        for (int i = 0; i < 4; i++) {
            short8v ahf = *(const short8v*)&Ash[cur][0][aFr[i]];
            short8v alf = *(const short8v*)&Ash[cur][1][aFr[i]];
            #pragma unroll
            for (int z = 0; z < Z; z++) {
                #pragma unroll
                for (int j = 0; j < 2; j++) {
                    acc[z][i][j] = __builtin_amdgcn_mfma_f32_16x16x32_bf16(ahf, bhf[z][j], acc[z][i][j], 0, 0, 0);
                    acc[z][i][j] = __builtin_amdgcn_mfma_f32_16x16x32_bf16(ahf, blf[z][j], acc[z][i][j], 0, 0, 0);
                    acc[z][i][j] = __builtin_amdgcn_mfma_f32_16x16x32_bf16(alf, bhf[z][j], acc[z][i][j], 0, 0, 0);
                }
            }
        }
    }
    #undef STAGEZ
    // C/D layout: col = lane&15, row = quad*4 + reg  [m89/m91-verified]
    #pragma unroll
    for (int z = 0; z < Z; z++) {
        const int zeff = z + zobase;
        #pragma unroll
        for (int i = 0; i < 4; i++) {
            const int mrow = m0 + wm*64 + i*16 + quad*4;
            #pragma unroll
            for (int j = 0; j < 2; j++) {
                const int ncol = n0 + wn*32 + j*16 + lrow;
                if (OUTMODE == 1) {
                    if (zeff < zsplit) {
                        unsigned short* Ch = (unsigned short*)Cout1 + (size_t)zeff * sC;
                        unsigned short* Cl = Ch + loff;
                        #pragma unroll
                        for (int r = 0; r < 4; r += 2) {
                            const float v0 = acc[z][i][j][r] * alpha;
                            const float v1 = acc[z][i][j][r+1] * alpha;
                            ushort2 h2 = f2bf2(v0, v1);
                            ushort2 l2 = f2bf2(v0 - bf2f(h2.x), v1 - bf2f(h2.y));
                            Ch[(size_t)(mrow + r    ) * N + ncol] = h2.x;
                            Ch[(size_t)(mrow + r + 1) * N + ncol] = h2.y;
                            Cl[(size_t)(mrow + r    ) * N + ncol] = l2.x;
                            Cl[(size_t)(mrow + r + 1) * N + ncol] = l2.y;
                        }
                    } else {
                        unsigned short* Ch = (unsigned short*)Cout2;
                        unsigned short* Cl = Ch + loff;
                        const int bidx = mrow / TB, t0 = mrow % TB;
                        const size_t ad = (size_t)bidx * N * TB + (size_t)ncol * TB + t0;
                        const float v0 = acc[z][i][j][0], v1 = acc[z][i][j][1];
                        const float v2 = acc[z][i][j][2], v3 = acc[z][i][j][3];
                        ushort2 h01 = f2bf2(v0, v1), h23 = f2bf2(v2, v3);
                        ushort2 l01 = f2bf2(v0 - bf2f(h01.x), v1 - bf2f(h01.y));
                        ushort2 l23 = f2bf2(v2 - bf2f(h23.x), v3 - bf2f(h23.y));
                        ushort4 hv, lv;
                        hv.x = h01.x; hv.y = h01.y; hv.z = h23.x; hv.w = h23.y;
                        lv.x = l01.x; lv.y = l01.y; lv.z = l23.x; lv.w = l23.y;
                        *(ushort4*)&Ch[ad] = hv;
                        *(ushort4*)&Cl[ad] = lv;
                    }
                } else {
                    // f32 transposed: out[bidx][ncol][t0..t0+3], one b128 store
                    float* C = (float*)Cout2;
                    const int bidx = mrow / TB, t0 = mrow % TB;
                    f32x4 a4 = acc[z][i][j];
                    *(float4*)&C[((size_t)bidx * N + ncol) * TB + t0] = *(float4*)&a4;
                }
            }
        }
    }
}

// ------- K3: positional attention, MFMA flash, S^T=K*Q^T trick ------------------
// 2-phase double-buffered DMA staging: one raw s_barrier + vmcnt(0) per K-tile;
// tile kt+1 issued right after the barrier so HBM/L2 latency hides under compute.
// q,k pre-scaled by ALPHA_P at projection -> scores carry log2e/sqrt(dk); p=2^s.
// K/V LDS: pitch 64 shorts, swizzle p = row*8 + (cc ^ (row&7)). XCD-chunked grid.
__global__ __launch_bounds__(256) void k3_mfma(
    const unsigned short* __restrict__ qh, const unsigned short* __restrict__ ql,
    const unsigned short* __restrict__ kh, const unsigned short* __restrict__ kl,
    const unsigned short* __restrict__ vth, const unsigned short* __restrict__ vtl,
    float* __restrict__ out)
{
    // grid (4,16,16); HW round-robins flat id over 8 XCDs -> give each XCD a
    // contiguous chunk of 128 logical blocks = 32 complete (h,b) K/V sets.
    const int flat = blockIdx.x + (blockIdx.y << 2) + (blockIdx.z << 6);
    const int logical = ((flat & 7) << 7) | (flat >> 3);
    const int m0 = (logical & 3) * 64;
    const int h  = (logical >> 2) & 15;
    const int b  = logical >> 6;
    const int hoff = h * DK_;
    const size_t rowb = (size_t)b * S_;
    __shared__ __align__(16) unsigned short Ksh[2][64*64], Ksl[2][64*64];
    __shared__ __align__(16) unsigned short VTh[2][64*64], VTl[2][64*64];
    __shared__ __align__(16) unsigned short Ps[64][72];
    const int tid = threadIdx.x;
    const int w = tid >> 6, lane = tid & 63;
    const int lrow = lane & 15, quad = lane >> 4;
    // Q as B-operand (cols of S^T): hi/lo, 2 k-steps
    short8v bqh[2], bql[2];
    #pragma unroll
    for (int ks = 0; ks < 2; ks++) {
        const size_t qb = (rowb + m0 + w*16 + lrow) * D_ + hoff + ks*32 + quad*8;
        bqh[ks] = *(const short8v*)&qh[qb];
        bql[ks] = *(const short8v*)&ql[qb];
    }
    size_t kOff[2], vOff[2];
    int cb[2];
    #pragma unroll
    for (int j = 0; j < 2; j++) {
        const int p = w*128 + j*64 + lane;
        const int row = p >> 3;
        const int cc = (p & 7) ^ (row & 7);
        kOff[j] = (rowb + row) * D_ + hoff + cc*8;
        vOff[j] = ((size_t)b * D_ + hoff + row) * S_ + cc*8;
        cb[j] = (w*128 + j*64) * 8;
    }
    f32x4 o[4] = {};
    float lacc = 0.f;
    // prologue: stage tile 0 into buf 0
    #pragma unroll
    for (int j = 0; j < 2; j++) {
        ldlds16(kh  + kOff[j], &Ksh[0][cb[j]]);
        ldlds16(kl  + kOff[j], &Ksl[0][cb[j]]);
        ldlds16(vth + vOff[j], &VTh[0][cb[j]]);
        ldlds16(vtl + vOff[j], &VTl[0][cb[j]]);
    }
    for (int kt = 0; kt < 4; kt++) {
        const int cur = kt & 1;
        asm volatile("s_waitcnt vmcnt(0)" ::: "memory"); // own tile-kt DMA done
        asm volatile("s_barrier" ::: "memory");          // all waves: tile visible;
                                                         // all done reading buf[cur^1]
        if (kt < 3) {                                    // prefetch tile kt+1
            const int n01 = (kt + 1) * 64;
            #pragma unroll
            for (int j = 0; j < 2; j++) {
                ldlds16(kh  + kOff[j] + (size_t)n01 * D_, &Ksh[cur^1][cb[j]]);
                ldlds16(kl  + kOff[j] + (size_t)n01 * D_, &Ksl[cur^1][cb[j]]);
                ldlds16(vth + vOff[j] + n01,              &VTh[cur^1][cb[j]]);
                ldlds16(vtl + vOff[j] + n01,              &VTl[cur^1][cb[j]]);
            }
        }
        // S^T = K·Q^T: rows=keys (A=K), cols=queries (B=Q regs)
        f32x4 sa[4] = {};
        #pragma unroll
        for (int ks = 0; ks < 2; ks++) {
            #pragma unroll
            for (int jk = 0; jk < 4; jk++) {
                const int r = jk*16 + lrow, c = ks*4 + quad;
                const int off = ((r << 3) | (c ^ (r & 7))) * 8;
                short8v akh = *(const short8v*)&Ksh[cur][off];
                short8v akl = *(const short8v*)&Ksl[cur][off];
                sa[jk] = __builtin_amdgcn_mfma_f32_16x16x32_bf16(akh, bqh[ks], sa[jk], 0, 0, 0);
                sa[jk] = __builtin_amdgcn_mfma_f32_16x16x32_bf16(akl, bqh[ks], sa[jk], 0, 0, 0);
                sa[jk] = __builtin_amdgcn_mfma_f32_16x16x32_bf16(akh, bql[ks], sa[jk], 0, 0, 0);
            }
        }
        // p = 2^s (scale folded upstream); P[m][key] row-major, b64 per frag
        #pragma unroll
        for (int jk = 0; jk < 4; jk++) {
            float p0 = exp2_fast(sa[jk][0]);
            float p1 = exp2_fast(sa[jk][1]);
            float p2 = exp2_fast(sa[jk][2]);
            float p3 = exp2_fast(sa[jk][3]);
            lacc += (p0 + p1) + (p2 + p3);
            ushort2 p01 = f2bf2(p0, p1), p23 = f2bf2(p2, p3);
            ushort4 ph;
            ph.x = p01.x; ph.y = p01.y; ph.z = p23.x; ph.w = p23.y;
            *(ushort4*)&Ps[w*16 + lrow][jk*16 + quad*4] = ph;   // wave-private rows
        }
        // PV: O = P·V^T' — no barrier (wave-private P)
        #pragma unroll
        for (int ks = 0; ks < 2; ks++) {
            short8v ap = *(const short8v*)&Ps[w*16 + lrow][ks*32 + quad*8];
            #pragma unroll
            for (int nf = 0; nf < 4; nf++) {
                const int r = nf*16 + lrow, c = ks*4 + quad;
                const int off = ((r << 3) | (c ^ (r & 7))) * 8;
                short8v vH = *(const short8v*)&VTh[cur][off];
                short8v vL = *(const short8v*)&VTl[cur][off];
                o[nf] = __builtin_amdgcn_mfma_f32_16x16x32_bf16(ap, vH, o[nf], 0, 0, 0);
                o[nf] = __builtin_amdgcn_mfma_f32_16x16x32_bf16(ap, vL, o[nf], 0, 0, 0);
            }
        }
    }
    // l: lane holds partials for col m=lrow (its quad's keys) -> sum over quads
    lacc += __shfl_xor(lacc, 16);
    lacc += __shfl_xor(lacc, 32);
    #pragma unroll
    for (int r = 0; r < 4; r++) {
        const float linv = 1.0f / __shfl(lacc, quad*4 + r);
        #pragma unroll
        for (int nf = 0; nf < 4; nf++)
            out[(rowb + m0 + w*16 + quad*4 + r) * D_ + hoff + nf*16 + lrow] =
                o[nf][r] * linv;
    }
}

// ------- K6: channel attention, MFMA flash, S^T trick ---------------------------
// Same 2-phase double-buffered single-barrier structure as k3. dk=32.
// Wave owns 32 q-rows (2 m-frags). P hi-only b64. Out bf16 h/l.
// K LDS: pitch 32 (swz (row>>1)&3); V LDS: pitch 64 (swz row&7). XCD-chunked grid.
__global__ __launch_bounds__(256) void k6_mfma(
    const unsigned short* __restrict__ qch, const unsigned short* __restrict__ qcl,
    const unsigned short* __restrict__ kch, const unsigned short* __restrict__ kcl,
    const unsigned short* __restrict__ vth, const unsigned short* __restrict__ vtl,
    unsigned short* __restrict__ oh, unsigned short* __restrict__ ol)
{
    // grid (8,8,16): each XCD gets 128 contiguous logicals = 16 complete (h,b)
    // K/V working sets -> K/V fetched once per XCD instead of 8x.
    const int flat = blockIdx.x + (blockIdx.y << 3) + (blockIdx.z << 6);
    const int logical = ((flat & 7) << 7) | (flat >> 3);
    const int m0 = (logical & 7) << 7;
    const int h  = (logical >> 3) & 7;
    const int b  = logical >> 6;
    const int hoff = h * SK_;
    const size_t rowb = (size_t)b * D_;
    __shared__ __align__(16) unsigned short Ksh[2][64*32], Ksl[2][64*32];
    __shared__ __align__(16) unsigned short VTh[2][32*64], VTl[2][32*64];
    __shared__ __align__(16) unsigned short Ps[128][72];
    const int tid = threadIdx.x;
    const int w = tid >> 6, lane = tid & 63;
    const int lrow = lane & 15, quad = lane >> 4;
    short8v bqh[2], bql[2];
    #pragma unroll
    for (int i = 0; i < 2; i++) {
        const size_t qb = (rowb + m0 + w*32 + i*16 + lrow) * S_ + hoff + quad*8;
        bqh[i] = *(const short8v*)&qch[qb];
        bql[i] = *(const short8v*)&qcl[qb];
    }
    size_t kOff, vOff;
    {
        const int pK = w*64 + lane;
        const int rowK = pK >> 2;
        const int ccK = (pK & 3) ^ ((rowK >> 1) & 3);
        kOff = (rowb + rowK) * S_ + hoff + ccK*8;
        const int pV = w*64 + lane;
        const int rowV = pV >> 3;
        const int ccV = (pV & 7) ^ (rowV & 7);
        vOff = ((size_t)b * S_ + hoff + rowV) * D_ + ccV*8;
    }
    const int cb = w*64*8;
    f32x4 o[2][2] = {};
    float lacc[2] = {0.f, 0.f};
    // prologue: stage tile 0 into buf 0
    ldlds16(kch + kOff, &Ksh[0][cb]);
    ldlds16(kcl + kOff, &Ksl[0][cb]);
    ldlds16(vth + vOff, &VTh[0][cb]);
    ldlds16(vtl + vOff, &VTl[0][cb]);
    for (int kt = 0; kt < 16; kt++) {
        const int cur = kt & 1;
        asm volatile("s_waitcnt vmcnt(0)" ::: "memory"); // own tile-kt DMA done
        asm volatile("s_barrier" ::: "memory");          // all waves: tile visible;
                                                         // all done reading buf[cur^1]
        if (kt < 15) {                                   // prefetch tile kt+1
            const int n01 = (kt + 1) * 64;
            ldlds16(kch + kOff + (size_t)n01 * S_, &Ksh[cur^1][cb]);
            ldlds16(kcl + kOff + (size_t)n01 * S_, &Ksl[cur^1][cb]);
            ldlds16(vth + vOff + n01,              &VTh[cur^1][cb]);
            ldlds16(vtl + vOff + n01,              &VTl[cur^1][cb]);
        }
        // S^T = K·Q^T  (q,k pre-scaled by ALPHA_C)
        f32x4 sa[2][4] = {};
        #pragma unroll
        for (int jk = 0; jk < 4; jk++) {
            const int r = jk*16 + lrow;
            const int off = ((r << 2) | (quad ^ ((r >> 1) & 3))) * 8;
            short8v akh = *(const short8v*)&Ksh[cur][off];
            short8v akl = *(const short8v*)&Ksl[cur][off];
            #pragma unroll
            for (int i = 0; i < 2; i++) {
                sa[i][jk] = __builtin_amdgcn_mfma_f32_16x16x32_bf16(akh, bqh[i], sa[i][jk], 0, 0, 0);
                sa[i][jk] = __builtin_amdgcn_mfma_f32_16x16x32_bf16(akl, bqh[i], sa[i][jk], 0, 0, 0);
                sa[i][jk] = __builtin_amdgcn_mfma_f32_16x16x32_bf16(akh, bql[i], sa[i][jk], 0, 0, 0);
            }
        }
        // p = 2^s; P row-major [m][key], b64 writes, wave-private rows
        #pragma unroll
        for (int i = 0; i < 2; i++)
            #pragma unroll
            for (int jk = 0; jk < 4; jk++) {
                float p0 = exp2_fast(sa[i][jk][0]);
                float p1 = exp2_fast(sa[i][jk][1]);
                float p2 = exp2_fast(sa[i][jk][2]);
                float p3 = exp2_fast(sa[i][jk][3]);
                lacc[i] += (p0 + p1) + (p2 + p3);
                ushort2 p01 = f2bf2(p0, p1), p23 = f2bf2(p2, p3);
                ushort4 ph;
                ph.x = p01.x; ph.y = p01.y; ph.z = p23.x; ph.w = p23.y;
                *(ushort4*)&Ps[w*32 + i*16 + lrow][jk*16 + quad*4] = ph;
            }
        // PV (no barrier: P rows wave-private)
        #pragma unroll
        for (int ks = 0; ks < 2; ks++) {
            short8v ap[2];
            #pragma unroll
            for (int i = 0; i < 2; i++)
                ap[i] = *(const short8v*)&Ps[w*32 + i*16 + lrow][ks*32 + quad*8];
            #pragma unroll
            for (int nf = 0; nf < 2; nf++) {
                const int r = nf*16 + lrow, c = ks*4 + quad;
                const int off = ((r << 3) | (c ^ (r & 7))) * 8;
                short8v vHf = *(const short8v*)&VTh[cur][off];
                short8v vLf = *(const short8v*)&VTl[cur][off];
                #pragma unroll
                for (int i = 0; i < 2; i++) {
                    o[i][nf] = __builtin_amdgcn_mfma_f32_16x16x32_bf16(ap[i], vHf, o[i][nf], 0, 0, 0);
                    o[i][nf] = __builtin_amdgcn_mfma_f32_16x16x32_bf16(ap[i], vLf, o[i][nf], 0, 0, 0);
                }
            }
        }
    }
    #pragma unroll
    for (int i = 0; i < 2; i++) {
        lacc[i] += __shfl_xor(lacc[i], 16);
        lacc[i] += __shfl_xor(lacc[i], 32);
    }
    #pragma unroll
    for (int i = 0; i < 2; i++)
        #pragma unroll
        for (int r = 0; r < 4; r++) {
            const float linv = 1.0f / __shfl(lacc[i], quad*4 + r);
            const float v0 = o[i][0][r] * linv;
            const float v1 = o[i][1][r] * linv;
            ushort2 h2 = f2bf2(v0, v1);
            ushort2 l2 = f2bf2(v0 - bf2f(h2.x), v1 - bf2f(h2.y));
            const size_t idx =
                (rowb + m0 + w*32 + i*16 + quad*4 + r) * S_ + hoff + lrow;
            oh[idx]      = h2.x;
            oh[idx + 16] = h2.y;
            ol[idx]      = l2.x;
            ol[idx + 16] = l2.y;
        }
}

// ------- K4 fused: LN over seq (stats+normalize) + transpose, bf16 h/l out ------
// Block = (64 d-cols, one b). tile[256][65] f32 + partials. One pass over x.
__global__ __launch_bounds__(256) void k4_fused(
    const float* __restrict__ x, const float* __restrict__ a_c,
    const float* __restrict__ b_c, unsigned short* __restrict__ xth,
    unsigned short* __restrict__ xtl)
{
    const int d0 = blockIdx.x * 64, b = blockIdx.y;
    __shared__ float tile[256][65];
    __shared__ float part[8][64];
    __shared__ float stats[2][64];
    __shared__ float acs[256], bcs[256];
    const int tid = threadIdx.x;
    acs[tid] = a_c[tid];
    bcs[tid] = b_c[tid];
    const int dl = tid & 63, sq = tid >> 6;
    float s1 = 0.f, s2 = 0.f;
    #pragma unroll 8
    for (int u = 0; u < 64; u++) {
        const int srow = sq*64 + u;
        const float v = x[((size_t)(b*S_ + srow))*D_ + d0 + dl];
        tile[srow][dl] = v;
        s1 += v; s2 += v*v;
    }
    part[sq][dl] = s1; part[4+sq][dl] = s2;
    __syncthreads();
    if (tid < 64) {
        const float S = part[0][tid]+part[1][tid]+part[2][tid]+part[3][tid];
        const float Q = part[4][tid]+part[5][tid]+part[6][tid]+part[7][tid];
        const float mean = S / (float)S_;
        const float var  = fmaxf((Q - (float)S_*mean*mean)/(float)(S_-1), 0.f);
        stats[0][tid] = mean;
        stats[1][tid] = 1.f/(sqrtf(var)+EPS_);
    }
    __syncthreads();
    const int dd = tid >> 2, s00 = (tid & 3) * 64;
    const float mean = stats[0][dd], inv = stats[1][dd];
    const size_t obase = ((size_t)(b*D_ + d0 + dd))*S_ + s00;
    #pragma unroll
    for (int c = 0; c < 8; c++) {
        union { ushort u[8]; uint4 v4; } hb, lb;
        #pragma unroll
        for (int t = 0; t < 8; t += 2) {
            const int s = s00 + c*8 + t;
            const float v0 = acs[s]  *(tile[s][dd]  -mean)*inv + bcs[s];
            const float v1 = acs[s+1]*(tile[s+1][dd]-mean)*inv + bcs[s+1];
            ushort2 h2 = f2bf2(v0, v1);
            ushort2 l2 = f2bf2(v0 - bf2f(h2.x), v1 - bf2f(h2.y));
            hb.u[t] = h2.x; hb.u[t+1] = h2.y;
            lb.u[t] = l2.x; lb.u[t+1] = l2.y;
        }
        *(uint4*)&xth[obase + c*8] = hb.v4;
        *(uint4*)&xtl[obase + c*8] = lb.v4;
    }
}

extern "C" void kernel_launch(void* const* d_in, const int* in_sizes, int n_in,
                              void* d_out, int out_size, void* d_ws, size_t ws_size,
                              hipStream_t stream)
{
    const float* x   = (const float*)d_in[0];
    const float* Wp  = (const float*)d_in[1];
    const float* bp  = (const float*)d_in[2];
    const float* Wc  = (const float*)d_in[3];
    const float* bc  = (const float*)d_in[4];
    const float* a_p = (const float*)d_in[5];
    const float* b_p = (const float*)d_in[6];
    const float* a_c = (const float*)d_in[7];
    const float* b_c = (const float*)d_in[8];
    float* out = (float*)d_out;
    float* ws  = (float*)d_ws;
    const size_t NE = (size_t)B_ * S_ * D_;     // 4,194,304

    float* S0 = ws;             // xp h/l -> attn f32 -> vcT h/l
    float* S1 = ws + NE;        // q h/l -> xt h/l -> xcatt h/l
    float* S2 = ws + 2*NE;      // k h/l -> qc h/l
    float* S3 = ws + 3*NE;      // vT h/l -> kc h/l
    unsigned short* SW = (unsigned short*)(ws + 4*NE);

    const size_t baseBytes = 4*NE*sizeof(float);
    const bool big = ws_size >= baseBytes + (size_t)2 * 3 * D_ * D_ * sizeof(unsigned short) * 2;

    unsigned short* xh = (unsigned short*)S0;
    unsigned short* xl = xh + NE;
    unsigned short* q_h  = (unsigned short*)S1;
    unsigned short* k_h  = (unsigned short*)S2;
    unsigned short* vt_h = (unsigned short*)S3;

    // 1) LayerNorm over channels -> bf16 hi/lo
    k1_ln_p<<<dim3(B_*S_), 256, 0, stream>>>(x, a_p, b_p, xh, xl);

    // 2) QKV projection (z-fused 128x64 GEMM, 512 blocks = 2/CU): q,k row-major
    //    bf16 h/l (pre-scaled by ALPHA_P); v transposed bf16 h/l.
    if (big) {
        unsigned short* WTh = SW;
        unsigned short* WTl = WTh + (size_t)3 * D_ * D_;
        tsplit<<<dim3(D_/64, D_/64, 3), 256, 0, stream>>>(Wp, WTh, WTl, D_, D_);
        mm_z<1,3><<<dim3(512), 256, 0, stream>>>(
            xh, xl, WTh, WTl, bp, (void*)q_h, (void*)vt_h,
            B_*S_, D_, D_, (long)D_*D_, (long)D_, (long)(2*NE), (long)NE, S_,
            ALPHA_P, 2, 0, 4);
    } else {
        unsigned short* WTh = SW;
        unsigned short* WTl = WTh + (size_t)D_ * D_;
        for (int z = 0; z < 3; z++) {
            tsplit<<<dim3(D_/64, D_/64, 1), 256, 0, stream>>>(
                Wp + (size_t)z*D_*D_, WTh, WTl, D_, D_);
            mm_z<1,1><<<dim3(512), 256, 0, stream>>>(
                xh, xl, WTh, WTl, bp, (void*)q_h, (void*)vt_h,
                B_*S_, D_, D_, 0, (long)D_, (long)(2*NE), (long)NE, S_,
                ALPHA_P, 2, z, 4);
        }
    }

    // 3) positional attention (MFMA flash, S^T trick) -> attn f32 in S0 (xp dead)
    k3_mfma<<<dim3(S_/64, HP_, B_), 256, 0, stream>>>(
        q_h, q_h + NE, k_h, k_h + NE, vt_h, vt_h + NE, S0);

    // 4) fused LN over sequence + transpose -> xt bf16 h/l in S1 (q dead)
    unsigned short* xth = (unsigned short*)S1;
    k4_fused<<<dim3(D_/64, B_), 256, 0, stream>>>(S0, a_c, b_c, xth, xth + NE);

    // 5) channel weights + channel QKV (z-fused 128x64 GEMM, 512 blocks = 2/CU):
    //    qc,kc row-major (pre-scaled by ALPHA_C); vc transposed
    unsigned short* WcTh = SW;
    unsigned short* WcTl = WcTh + (size_t)4 * S_ * S_;
    tsplit<<<dim3(S_/64, S_/64, 4), 256, 0, stream>>>(Wc, WcTh, WcTl, S_, S_);
    unsigned short* qc_h  = (unsigned short*)S2;   // k dead
    unsigned short* vct_h = (unsigned short*)S0;   // attn f32 dead after k4
    mm_z<1,3><<<dim3(512), 256, 0, stream>>>(
        xth, xth + NE, WcTh, WcTl, bc, (void*)qc_h, (void*)vct_h,
        B_*D_, S_, S_, (long)S_*S_, (long)S_, (long)(2*NE), (long)NE, D_,
        ALPHA_C, 2, 0, 2);

    // 6) channel attention (MFMA flash, S^T trick) -> xcatt bf16 h/l in S1 (xt dead)
    unsigned short* kc_h = (unsigned short*)S3;
    unsigned short* xch  = (unsigned short*)S1;
    k6_mfma<<<dim3(D_/128, HC_, B_), 256, 0, stream>>>(
        qc_h, qc_h + NE, kc_h, kc_h + NE, vct_h, vct_h + NE, xch, xch + NE);

    // 7) final projection -> out directly (f32 transposed epilogue)
    mm_z<3,1><<<dim3(512), 256, 0, stream>>>(
        xch, xch + NE, WcTh + (size_t)3*S_*S_, WcTl + (size_t)3*S_*S_, bc + 3*S_,
        nullptr, (void*)out, B_*D_, S_, S_, 0, 0, 0, 0, D_, 1.0f, 0, 0, 2);
}